// Round 4
// baseline (1335.257 us; speedup 1.0000x reference)
//
#include <hip/hip_runtime.h>

// GumbelVQ — 3-pass streaming, row split across 2 waves for occupancy.
// Outputs (concatenated float32 in d_out):
//   [0 .. 8388607]      quantized  [16,16384,32]
//   [8388608]           commitment_loss (scalar)
//   [8388609 .. 8650752] indices   [16,16384] (stored as float)
//   [8650753]           perplexity (scalar)
//
// ws float layout:
//   [0..255]    avg_probs accumulator
//   [256]       loss accumulator
//   [257..512]  ||e_k||^2
//   [1024 .. 1024+M)  invS per row
//   floats from 1024+M : p (unnormalized numerators) bf16 [M][256]
//
// Round-4 fix: round-3 counters (Occ 43%, VALU 34%, HBM 13%) = latency-bound
// with a half-empty machine (4096 waves vs 8192 slots). Split each row's 256
// codes across two threads in different waves of one block (half = tid>>7, so
// per-wave embedding addresses remain wave-uniform); combine ssum/argmax (and
// q in pass2) through small LDS. Grid 2048 blocks, launch_bounds(256,8).

#define M_ROWS  262144
#define OUT_LOSS 8388608
#define OUT_IDX  8388609
#define OUT_PPL  8650753

__device__ __forceinline__ unsigned int f2bf_u(float f) {
  unsigned int u = __float_as_uint(f);
  u += 0x7fffu + ((u >> 16) & 1u);
  return u >> 16;
}
__device__ __forceinline__ float bf2f(unsigned int lo16) {
  return __uint_as_float(lo16 << 16);
}

__global__ __launch_bounds__(256) void vq_prep(const float* __restrict__ emb,
                                               float* __restrict__ ws) {
  int t = threadIdx.x;
  ws[t] = 0.0f;                 // avg accumulators
  if (t == 0) ws[256] = 0.0f;   // loss accumulator
  const float4* e4 = (const float4*)emb;
  float s = 0.0f;
#pragma unroll
  for (int j = 0; j < 8; ++j) {
    float4 v = e4[t * 8 + j];
    s += v.x * v.x + v.y * v.y + v.z * v.z + v.w * v.w;
  }
  ws[257 + t] = s;
}

// ---- pass 1: logits, p(bf16)->ws, invS, argmax->indices, loss ---------------
// 2048 blocks x 256 thr; block owns 128 rows; half = tid>>7 owns 128 codes.
__global__ __launch_bounds__(256, 8) void vq_pass1(
    const float* __restrict__ x_in, const float* __restrict__ emb,
    const float* __restrict__ gum, const float* __restrict__ ne,
    float* __restrict__ invS_ws, unsigned short* __restrict__ p_ws,
    float* __restrict__ loss_ws, float* __restrict__ out) {
  __shared__ float sh_ssum[128];
  __shared__ float sh_tmax[128];
  __shared__ int   sh_imax[128];

  const int tid  = threadIdx.x;
  const int lane = tid & 63;
  const int rloc = tid & 127;
  const int half = tid >> 7;                // wave-uniform
  const int row  = blockIdx.x * 128 + rloc;
  const int kbase = half * 128;

  float xr[32];
  {
    const float4* xv = (const float4*)(x_in + (size_t)row * 32);
#pragma unroll
    for (int j = 0; j < 8; ++j) {
      float4 v = xv[j];
      xr[4*j+0] = v.x; xr[4*j+1] = v.y; xr[4*j+2] = v.z; xr[4*j+3] = v.w;
    }
  }

  const float4* g4 = (const float4*)(gum + (size_t)row * 256 + kbase);
  const float4* e4 = (const float4*)emb;
  uint4* pout = (uint4*)(p_ws + (size_t)row * 256 + kbase);

  float ssum = 0.0f;
  float tmax = -3.0e38f;
  int   imax = 0;

  for (int kg = 0; kg < 4; ++kg) {          // 4 groups of 32 codes
    float uv[32];
#pragma unroll
    for (int j = 0; j < 8; ++j) {
      float4 v = g4[kg * 8 + j];
      uv[4*j+0] = v.x; uv[4*j+1] = v.y; uv[4*j+2] = v.z; uv[4*j+3] = v.w;
    }
    unsigned int packs[16];
#pragma unroll
    for (int kk = 0; kk < 32; ++kk) {
      const int k = kbase + kg * 32 + kk;
      const float g = -__logf(-__logf(uv[kk] + 1e-20f) + 1e-20f);
      float d0 = 0.f, d1 = 0.f, d2 = 0.f, d3 = 0.f;
#pragma unroll
      for (int jj = 0; jj < 8; ++jj) {
        const float4 e = e4[k * 8 + jj];    // wave-uniform address
        d0 = fmaf(xr[4*jj+0], e.x, d0);
        d1 = fmaf(xr[4*jj+1], e.y, d1);
        d2 = fmaf(xr[4*jj+2], e.z, d2);
        d3 = fmaf(xr[4*jj+3], e.w, d3);
      }
      const float dot = (d0 + d1) + (d2 + d3);
      const float t = fmaf(2.0f, dot, g) - ne[k];  // ||x||^2 const per row
      const float p = __expf(t);
      ssum += p;
      if (t > tmax) { tmax = t; imax = k; }
      if (kk & 1) packs[kk >> 1] |= f2bf_u(p) << 16;
      else        packs[kk >> 1]  = f2bf_u(p);
    }
    const uint4* pd = (const uint4*)packs;
#pragma unroll
    for (int j = 0; j < 4; ++j) pout[kg * 4 + j] = pd[j];  // full 64B line
  }

  if (half == 1) {
    sh_ssum[rloc] = ssum; sh_tmax[rloc] = tmax; sh_imax[rloc] = imax;
  }
  __syncthreads();
  if (half == 0) {
    const float sB = sh_ssum[rloc];
    const float tB = sh_tmax[rloc];
    const int   iB = sh_imax[rloc];
    if (tB > tmax) { tmax = tB; imax = iB; }   // strict > keeps first-index ties
    invS_ws[row] = 1.0f / (ssum + sB);
    out[OUT_IDX + row] = (float)imax;

    // commitment loss: (e_hard - x)^2 summed; e gather is L1-resident (32KB)
    const float4* ehv = (const float4*)(emb + (size_t)imax * 32);
    float cl = 0.0f;
#pragma unroll
    for (int j = 0; j < 8; ++j) {
      float4 e = ehv[j];
      float dx;
      dx = e.x - xr[4*j+0]; cl = fmaf(dx, dx, cl);
      dx = e.y - xr[4*j+1]; cl = fmaf(dx, dx, cl);
      dx = e.z - xr[4*j+2]; cl = fmaf(dx, dx, cl);
      dx = e.w - xr[4*j+3]; cl = fmaf(dx, dx, cl);
    }
#pragma unroll
    for (int off = 32; off > 0; off >>= 1) cl += __shfl_down(cl, off);
    if (lane == 0) atomicAdd(loss_ws, cl);
  }
}

// ---- pass 2: quantized = tr * (p-hat @ E) + (1-tr) * e_hard -----------------
// Same split: half-B accumulates q over codes 128..255, hands it over via LDS.
__global__ __launch_bounds__(256, 8) void vq_pass2(
    const float* __restrict__ emb, const unsigned short* __restrict__ p_ws,
    const float* __restrict__ invS_ws, float* __restrict__ out) {
  __shared__ float shq[128][33];            // +1 pad: conflict-free columns

  const int tid  = threadIdx.x;
  const int rloc = tid & 127;
  const int half = tid >> 7;                // wave-uniform
  const int row  = blockIdx.x * 128 + rloc;
  const int kbase = half * 128;

  const uint4* pv = (const uint4*)(p_ws + (size_t)row * 256 + kbase);
  const float4* e4 = (const float4*)emb;

  float q[32];
#pragma unroll
  for (int d = 0; d < 32; ++d) q[d] = 0.0f;

  for (int i = 0; i < 8; ++i) {             // 8 uint4 = 64B = 32 codes... x4
    const uint4 v = pv[i];
    unsigned int w_[4] = {v.x, v.y, v.z, v.w};
#pragma unroll
    for (int h = 0; h < 4; ++h) {
      const int k0 = kbase + i * 8 + 2 * h;
      const float p0 = bf2f(w_[h] & 0xffffu);
      const float p1 = bf2f(w_[h] >> 16);
#pragma unroll
      for (int jj = 0; jj < 8; ++jj) {
        const float4 e0 = e4[k0 * 8 + jj];        // wave-uniform
        const float4 e1 = e4[(k0 + 1) * 8 + jj];
        q[4*jj+0] = fmaf(p0, e0.x, fmaf(p1, e1.x, q[4*jj+0]));
        q[4*jj+1] = fmaf(p0, e0.y, fmaf(p1, e1.y, q[4*jj+1]));
        q[4*jj+2] = fmaf(p0, e0.z, fmaf(p1, e1.z, q[4*jj+2]));
        q[4*jj+3] = fmaf(p0, e0.w, fmaf(p1, e1.w, q[4*jj+3]));
      }
    }
  }

  if (half == 1) {
#pragma unroll
    for (int d = 0; d < 32; ++d) shq[rloc][d] = q[d];
  }
  __syncthreads();
  if (half == 0) {
    const float invS = invS_ws[row];
    const int imax = (int)out[OUT_IDX + row];
    const float tr  = 1.0f / 3.0f;     // (1.0-0.5)/(2.0-0.5)
    const float otr = 1.0f - tr;
    const float4* ehv = (const float4*)(emb + (size_t)imax * 32);
    float4* outq = (float4*)(out + (size_t)row * 32);
#pragma unroll
    for (int j = 0; j < 8; ++j) {
      float4 e = ehv[j];
      float4 o;
      o.x = fmaf(tr, (q[4*j+0] + shq[rloc][4*j+0]) * invS, otr * e.x);
      o.y = fmaf(tr, (q[4*j+1] + shq[rloc][4*j+1]) * invS, otr * e.y);
      o.z = fmaf(tr, (q[4*j+2] + shq[rloc][4*j+2]) * invS, otr * e.z);
      o.w = fmaf(tr, (q[4*j+3] + shq[rloc][4*j+3]) * invS, otr * e.w);
      outq[j] = o;
    }
  }
}

// ---- pass 2b: avg_probs column sums (coalesced, 4096 waves) -----------------
__global__ __launch_bounds__(256) void vq_avg(
    const unsigned short* __restrict__ p_ws, const float* __restrict__ invS_ws,
    float* __restrict__ avg_ws) {
  __shared__ float sh[256];
  const int tid = threadIdx.x, lane = tid & 63, w = tid >> 6;
  sh[tid] = 0.0f;
  __syncthreads();
  const int base = (blockIdx.x * 4 + w) * 64;   // 4096 waves, 64 rows each
  const float iv = invS_ws[base + lane];
  float a0 = 0.f, a1 = 0.f, a2 = 0.f, a3 = 0.f;
  for (int r = 0; r < 64; ++r) {
    const float s = __shfl(iv, r);
    const unsigned short* pr = p_ws + (size_t)(base + r) * 256;
    a0 = fmaf(bf2f(pr[  0 + lane]), s, a0);
    a1 = fmaf(bf2f(pr[ 64 + lane]), s, a1);
    a2 = fmaf(bf2f(pr[128 + lane]), s, a2);
    a3 = fmaf(bf2f(pr[192 + lane]), s, a3);
  }
  atomicAdd(&sh[  0 + lane], a0);
  atomicAdd(&sh[ 64 + lane], a1);
  atomicAdd(&sh[128 + lane], a2);
  atomicAdd(&sh[192 + lane], a3);
  __syncthreads();
  atomicAdd(&avg_ws[tid], sh[tid]);
}

__global__ __launch_bounds__(256) void vq_fin(const float* __restrict__ ws,
                                              float* __restrict__ out) {
  __shared__ float red[256];
  int t = threadIdx.x;
  float avg = ws[t] * (1.0f / 262144.0f);
  red[t] = -avg * __logf(avg + 1e-10f);
  __syncthreads();
  for (int s = 128; s > 0; s >>= 1) {
    if (t < s) red[t] += red[t + s];
    __syncthreads();
  }
  if (t == 0) {
    out[OUT_PPL]  = __expf(red[0]);
    out[OUT_LOSS] = ws[256] * (1.0f / 8388608.0f);
  }
}

// ---- fallback (round-1 monolithic, if ws too small) -------------------------
__global__ __launch_bounds__(256, 1) void vq_main(
    const float* __restrict__ x_in, const float* __restrict__ emb,
    const float* __restrict__ gum, const float* __restrict__ ne,
    float* __restrict__ avg_ws, float* __restrict__ loss_ws,
    float* __restrict__ out) {
  extern __shared__ unsigned char dynsmem[];
  unsigned short* p_lds = (unsigned short*)dynsmem;

  const int tid  = threadIdx.x;
  const int lane = tid & 63;
  const int w    = tid >> 6;
  const int row  = blockIdx.x * 256 + tid;
  unsigned short* my_p = p_lds + (size_t)(w * 64 + lane) * 258;

  float xr[32];
  {
    const float4* xv = (const float4*)(x_in + (size_t)row * 32);
#pragma unroll
    for (int j = 0; j < 8; ++j) {
      float4 v = xv[j];
      xr[4*j+0] = v.x; xr[4*j+1] = v.y; xr[4*j+2] = v.z; xr[4*j+3] = v.w;
    }
  }
  float q[32];
#pragma unroll
  for (int d = 0; d < 32; ++d) q[d] = 0.0f;

  float ssum = 0.0f;
  float tmax = -3.0e38f;
  int   imax = 0;

  const float4* g4 = (const float4*)(gum + (size_t)row * 256);
  const float4* e4 = (const float4*)emb;

  for (int kg = 0; kg < 8; ++kg) {
    float uv[32];
#pragma unroll
    for (int j = 0; j < 8; ++j) {
      float4 v = g4[kg * 8 + j];
      uv[4*j+0] = v.x; uv[4*j+1] = v.y; uv[4*j+2] = v.z; uv[4*j+3] = v.w;
    }
#pragma unroll
    for (int kk = 0; kk < 32; ++kk) {
      const int k = kg * 32 + kk;
      float er[32];
#pragma unroll
      for (int j = 0; j < 8; ++j) {
        float4 v = e4[k * 8 + j];
        er[4*j+0] = v.x; er[4*j+1] = v.y; er[4*j+2] = v.z; er[4*j+3] = v.w;
      }
      float d0 = 0.f, d1 = 0.f, d2 = 0.f, d3 = 0.f;
#pragma unroll
      for (int d = 0; d < 32; d += 4) {
        d0 = fmaf(xr[d+0], er[d+0], d0);
        d1 = fmaf(xr[d+1], er[d+1], d1);
        d2 = fmaf(xr[d+2], er[d+2], d2);
        d3 = fmaf(xr[d+3], er[d+3], d3);
      }
      const float dot = (d0 + d1) + (d2 + d3);
      const float inner = -__logf(uv[kk] + 1e-20f);
      const float g = -__logf(inner + 1e-20f);
      const float t = fmaf(2.0f, dot, g) - ne[k];
      const float p = __expf(t);
      ssum += p;
      if (t > tmax) { tmax = t; imax = k; }
#pragma unroll
      for (int d = 0; d < 32; ++d) q[d] = fmaf(p, er[d], q[d]);
      my_p[k] = (unsigned short)f2bf_u(p);
    }
  }

  const float invS = 1.0f / ssum;
  {
    const float tr  = 1.0f / 3.0f;
    const float otr = 1.0f - tr;
    const float4* ehv = (const float4*)(emb + (size_t)imax * 32);
    float4* outq = (float4*)(out + (size_t)row * 32);
    float cl = 0.0f;
#pragma unroll
    for (int j = 0; j < 8; ++j) {
      float4 e = ehv[j];
      float4 o;
      float qs, dx;
      qs = q[4*j+0]*invS; o.x = tr*qs + otr*e.x; dx = e.x - xr[4*j+0]; cl = fmaf(dx,dx,cl);
      qs = q[4*j+1]*invS; o.y = tr*qs + otr*e.y; dx = e.y - xr[4*j+1]; cl = fmaf(dx,dx,cl);
      qs = q[4*j+2]*invS; o.z = tr*qs + otr*e.z; dx = e.z - xr[4*j+2]; cl = fmaf(dx,dx,cl);
      qs = q[4*j+3]*invS; o.w = tr*qs + otr*e.w; dx = e.w - xr[4*j+3]; cl = fmaf(dx,dx,cl);
      outq[j] = o;
    }
    out[OUT_IDX + row] = (float)imax;
#pragma unroll
    for (int off = 32; off > 0; off >>= 1) cl += __shfl_down(cl, off);
    if (lane == 0) atomicAdd(loss_ws, cl);
  }

  __syncthreads();

  float a0 = 0.f, a1 = 0.f, a2 = 0.f, a3 = 0.f;
  for (int r = 0; r < 64; ++r) {
    const float invS_r = __shfl(invS, r);
    const unsigned short* rp = p_lds + (size_t)(w * 64 + r) * 258;
    a0 = fmaf(bf2f(rp[  0 + lane]), invS_r, a0);
    a1 = fmaf(bf2f(rp[ 64 + lane]), invS_r, a1);
    a2 = fmaf(bf2f(rp[128 + lane]), invS_r, a2);
    a3 = fmaf(bf2f(rp[192 + lane]), invS_r, a3);
  }
  atomicAdd(&avg_ws[  0 + lane], a0);
  atomicAdd(&avg_ws[ 64 + lane], a1);
  atomicAdd(&avg_ws[128 + lane], a2);
  atomicAdd(&avg_ws[192 + lane], a3);
}

extern "C" void kernel_launch(void* const* d_in, const int* in_sizes, int n_in,
                              void* d_out, int out_size, void* d_ws, size_t ws_size,
                              hipStream_t stream) {
  const float* x   = (const float*)d_in[0];
  const float* emb = (const float*)d_in[1];
  const float* gum = (const float*)d_in[2];
  float* out = (float*)d_out;
  float* ws  = (float*)d_ws;

  (void)in_sizes; (void)n_in; (void)out_size;

  vq_prep<<<1, 256, 0, stream>>>(emb, ws);

  const size_t need = (size_t)(1024 + M_ROWS) * 4 + (size_t)M_ROWS * 256 * 2;
  if (ws_size >= need) {
    float* invS = ws + 1024;
    unsigned short* p = (unsigned short*)(ws + 1024 + M_ROWS);
    vq_pass1<<<2048, 256, 0, stream>>>(x, emb, gum, ws + 257, invS, p, ws + 256, out);
    vq_pass2<<<2048, 256, 0, stream>>>(emb, p, invS, out);
    vq_avg<<<1024, 256, 0, stream>>>(p, invS, ws);
  } else {
    hipFuncSetAttribute((const void*)vq_main,
                        hipFuncAttributeMaxDynamicSharedMemorySize, 132128);
    vq_main<<<1024, 256, 132128, stream>>>(x, emb, gum, ws + 257, ws, ws + 256, out);
  }
  vq_fin<<<1, 256, 0, stream>>>(ws, out);
}

// Round 5
// 819.838 us; speedup vs baseline: 1.6287x; 1.6287x over previous
//
#include <hip/hip_runtime.h>

// GumbelVQ — 3-pass streaming, row split across 2 wave-halves for occupancy.
// Outputs (concatenated float32 in d_out):
//   [0 .. 8388607]      quantized  [16,16384,32]
//   [8388608]           commitment_loss (scalar)
//   [8388609 .. 8650752] indices   [16,16384] (stored as float)
//   [8650753]           perplexity (scalar)
//
// ws float layout:
//   [0..255]    avg_probs accumulator
//   [256]       loss accumulator
//   [257..512]  ||e_k||^2
//   [1024 .. 1024+M)  invS per row
//   floats from 1024+M : p (unnormalized numerators) bf16 [M][256]
//
// Round-5 fixes vs round-4:
//  - launch_bounds (256,8)->(256,4): the 8-wave cap forced VGPR=32 and spilled
//    2.7 GB of scratch traffic (FETCH 1.76 GB, VALU 14%). Round-3's identical
//    inner loop under (256,4) compiled to 60 VGPR <= 64, which already permits
//    8 waves/SIMD — the grid, not the bound, must supply the waves (2048 blocks).
//  - pass2 bug: p-read loop covered only 64 of 128 codes per half (i<8 -> i<16).

#define M_ROWS  262144
#define OUT_LOSS 8388608
#define OUT_IDX  8388609
#define OUT_PPL  8650753

__device__ __forceinline__ unsigned int f2bf_u(float f) {
  unsigned int u = __float_as_uint(f);
  u += 0x7fffu + ((u >> 16) & 1u);
  return u >> 16;
}
__device__ __forceinline__ float bf2f(unsigned int lo16) {
  return __uint_as_float(lo16 << 16);
}

__global__ __launch_bounds__(256) void vq_prep(const float* __restrict__ emb,
                                               float* __restrict__ ws) {
  int t = threadIdx.x;
  ws[t] = 0.0f;                 // avg accumulators
  if (t == 0) ws[256] = 0.0f;   // loss accumulator
  const float4* e4 = (const float4*)emb;
  float s = 0.0f;
#pragma unroll
  for (int j = 0; j < 8; ++j) {
    float4 v = e4[t * 8 + j];
    s += v.x * v.x + v.y * v.y + v.z * v.z + v.w * v.w;
  }
  ws[257 + t] = s;
}

// ---- pass 1: logits, p(bf16)->ws, invS, argmax->indices, loss ---------------
// 2048 blocks x 256 thr; block owns 128 rows; half = tid>>7 owns 128 codes.
__global__ __launch_bounds__(256, 4) void vq_pass1(
    const float* __restrict__ x_in, const float* __restrict__ emb,
    const float* __restrict__ gum, const float* __restrict__ ne,
    float* __restrict__ invS_ws, unsigned short* __restrict__ p_ws,
    float* __restrict__ loss_ws, float* __restrict__ out) {
  __shared__ float sh_ssum[128];
  __shared__ float sh_tmax[128];
  __shared__ int   sh_imax[128];

  const int tid  = threadIdx.x;
  const int lane = tid & 63;
  const int rloc = tid & 127;
  const int half = tid >> 7;                // wave-uniform
  const int row  = blockIdx.x * 128 + rloc;
  const int kbase = half * 128;

  float xr[32];
  {
    const float4* xv = (const float4*)(x_in + (size_t)row * 32);
#pragma unroll
    for (int j = 0; j < 8; ++j) {
      float4 v = xv[j];
      xr[4*j+0] = v.x; xr[4*j+1] = v.y; xr[4*j+2] = v.z; xr[4*j+3] = v.w;
    }
  }

  const float4* g4 = (const float4*)(gum + (size_t)row * 256 + kbase);
  const float4* e4 = (const float4*)emb;
  uint4* pout = (uint4*)(p_ws + (size_t)row * 256 + kbase);

  float ssum = 0.0f;
  float tmax = -3.0e38f;
  int   imax = 0;

  for (int kg = 0; kg < 4; ++kg) {          // 4 groups of 32 codes
    float uv[32];
#pragma unroll
    for (int j = 0; j < 8; ++j) {
      float4 v = g4[kg * 8 + j];
      uv[4*j+0] = v.x; uv[4*j+1] = v.y; uv[4*j+2] = v.z; uv[4*j+3] = v.w;
    }
    unsigned int packs[16];
#pragma unroll
    for (int kk = 0; kk < 32; ++kk) {
      const int k = kbase + kg * 32 + kk;
      const float g = -__logf(-__logf(uv[kk] + 1e-20f) + 1e-20f);
      float d0 = 0.f, d1 = 0.f, d2 = 0.f, d3 = 0.f;
#pragma unroll
      for (int jj = 0; jj < 8; ++jj) {
        const float4 e = e4[k * 8 + jj];    // wave-uniform address
        d0 = fmaf(xr[4*jj+0], e.x, d0);
        d1 = fmaf(xr[4*jj+1], e.y, d1);
        d2 = fmaf(xr[4*jj+2], e.z, d2);
        d3 = fmaf(xr[4*jj+3], e.w, d3);
      }
      const float dot = (d0 + d1) + (d2 + d3);
      const float t = fmaf(2.0f, dot, g) - ne[k];  // ||x||^2 const per row
      const float p = __expf(t);
      ssum += p;
      if (t > tmax) { tmax = t; imax = k; }
      if (kk & 1) packs[kk >> 1] |= f2bf_u(p) << 16;
      else        packs[kk >> 1]  = f2bf_u(p);
    }
    const uint4* pd = (const uint4*)packs;
#pragma unroll
    for (int j = 0; j < 4; ++j) pout[kg * 4 + j] = pd[j];  // full 64B line
  }

  if (half == 1) {
    sh_ssum[rloc] = ssum; sh_tmax[rloc] = tmax; sh_imax[rloc] = imax;
  }
  __syncthreads();
  if (half == 0) {
    const float sB = sh_ssum[rloc];
    const float tB = sh_tmax[rloc];
    const int   iB = sh_imax[rloc];
    if (tB > tmax) { tmax = tB; imax = iB; }   // strict > keeps first-index ties
    invS_ws[row] = 1.0f / (ssum + sB);
    out[OUT_IDX + row] = (float)imax;

    // commitment loss: (e_hard - x)^2 summed; e gather is L1-resident (32KB)
    const float4* ehv = (const float4*)(emb + (size_t)imax * 32);
    float cl = 0.0f;
#pragma unroll
    for (int j = 0; j < 8; ++j) {
      float4 e = ehv[j];
      float dx;
      dx = e.x - xr[4*j+0]; cl = fmaf(dx, dx, cl);
      dx = e.y - xr[4*j+1]; cl = fmaf(dx, dx, cl);
      dx = e.z - xr[4*j+2]; cl = fmaf(dx, dx, cl);
      dx = e.w - xr[4*j+3]; cl = fmaf(dx, dx, cl);
    }
#pragma unroll
    for (int off = 32; off > 0; off >>= 1) cl += __shfl_down(cl, off);
    if (lane == 0) atomicAdd(loss_ws, cl);
  }
}

// ---- pass 2: quantized = tr * (p-hat @ E) + (1-tr) * e_hard -----------------
// Same split: half-B accumulates q over codes 128..255, hands it over via LDS.
__global__ __launch_bounds__(256, 4) void vq_pass2(
    const float* __restrict__ emb, const unsigned short* __restrict__ p_ws,
    const float* __restrict__ invS_ws, float* __restrict__ out) {
  __shared__ float shq[128][33];            // +1 pad: conflict-free columns

  const int tid  = threadIdx.x;
  const int rloc = tid & 127;
  const int half = tid >> 7;                // wave-uniform
  const int row  = blockIdx.x * 128 + rloc;
  const int kbase = half * 128;

  const uint4* pv = (const uint4*)(p_ws + (size_t)row * 256 + kbase);
  const float4* e4 = (const float4*)emb;

  float q[32];
#pragma unroll
  for (int d = 0; d < 32; ++d) q[d] = 0.0f;

  for (int i = 0; i < 16; ++i) {            // 16 uint4 = 128 codes per half
    const uint4 v = pv[i];
    unsigned int w_[4] = {v.x, v.y, v.z, v.w};
#pragma unroll
    for (int h = 0; h < 4; ++h) {
      const int k0 = kbase + i * 8 + 2 * h;
      const float p0 = bf2f(w_[h] & 0xffffu);
      const float p1 = bf2f(w_[h] >> 16);
#pragma unroll
      for (int jj = 0; jj < 8; ++jj) {
        const float4 e0 = e4[k0 * 8 + jj];        // wave-uniform
        const float4 e1 = e4[(k0 + 1) * 8 + jj];
        q[4*jj+0] = fmaf(p0, e0.x, fmaf(p1, e1.x, q[4*jj+0]));
        q[4*jj+1] = fmaf(p0, e0.y, fmaf(p1, e1.y, q[4*jj+1]));
        q[4*jj+2] = fmaf(p0, e0.z, fmaf(p1, e1.z, q[4*jj+2]));
        q[4*jj+3] = fmaf(p0, e0.w, fmaf(p1, e1.w, q[4*jj+3]));
      }
    }
  }

  if (half == 1) {
#pragma unroll
    for (int d = 0; d < 32; ++d) shq[rloc][d] = q[d];
  }
  __syncthreads();
  if (half == 0) {
    const float invS = invS_ws[row];
    const int imax = (int)out[OUT_IDX + row];
    const float tr  = 1.0f / 3.0f;     // (1.0-0.5)/(2.0-0.5)
    const float otr = 1.0f - tr;
    const float4* ehv = (const float4*)(emb + (size_t)imax * 32);
    float4* outq = (float4*)(out + (size_t)row * 32);
#pragma unroll
    for (int j = 0; j < 8; ++j) {
      float4 e = ehv[j];
      float4 o;
      o.x = fmaf(tr, (q[4*j+0] + shq[rloc][4*j+0]) * invS, otr * e.x);
      o.y = fmaf(tr, (q[4*j+1] + shq[rloc][4*j+1]) * invS, otr * e.y);
      o.z = fmaf(tr, (q[4*j+2] + shq[rloc][4*j+2]) * invS, otr * e.z);
      o.w = fmaf(tr, (q[4*j+3] + shq[rloc][4*j+3]) * invS, otr * e.w);
      outq[j] = o;
    }
  }
}

// ---- pass 2b: avg_probs column sums (coalesced, 4096 waves) -----------------
__global__ __launch_bounds__(256) void vq_avg(
    const unsigned short* __restrict__ p_ws, const float* __restrict__ invS_ws,
    float* __restrict__ avg_ws) {
  __shared__ float sh[256];
  const int tid = threadIdx.x, lane = tid & 63, w = tid >> 6;
  sh[tid] = 0.0f;
  __syncthreads();
  const int base = (blockIdx.x * 4 + w) * 64;   // 4096 waves, 64 rows each
  const float iv = invS_ws[base + lane];
  float a0 = 0.f, a1 = 0.f, a2 = 0.f, a3 = 0.f;
  for (int r = 0; r < 64; ++r) {
    const float s = __shfl(iv, r);
    const unsigned short* pr = p_ws + (size_t)(base + r) * 256;
    a0 = fmaf(bf2f(pr[  0 + lane]), s, a0);
    a1 = fmaf(bf2f(pr[ 64 + lane]), s, a1);
    a2 = fmaf(bf2f(pr[128 + lane]), s, a2);
    a3 = fmaf(bf2f(pr[192 + lane]), s, a3);
  }
  atomicAdd(&sh[  0 + lane], a0);
  atomicAdd(&sh[ 64 + lane], a1);
  atomicAdd(&sh[128 + lane], a2);
  atomicAdd(&sh[192 + lane], a3);
  __syncthreads();
  atomicAdd(&avg_ws[tid], sh[tid]);
}

__global__ __launch_bounds__(256) void vq_fin(const float* __restrict__ ws,
                                              float* __restrict__ out) {
  __shared__ float red[256];
  int t = threadIdx.x;
  float avg = ws[t] * (1.0f / 262144.0f);
  red[t] = -avg * __logf(avg + 1e-10f);
  __syncthreads();
  for (int s = 128; s > 0; s >>= 1) {
    if (t < s) red[t] += red[t + s];
    __syncthreads();
  }
  if (t == 0) {
    out[OUT_PPL]  = __expf(red[0]);
    out[OUT_LOSS] = ws[256] * (1.0f / 8388608.0f);
  }
}

// ---- fallback (round-1 monolithic, if ws too small) -------------------------
__global__ __launch_bounds__(256, 1) void vq_main(
    const float* __restrict__ x_in, const float* __restrict__ emb,
    const float* __restrict__ gum, const float* __restrict__ ne,
    float* __restrict__ avg_ws, float* __restrict__ loss_ws,
    float* __restrict__ out) {
  extern __shared__ unsigned char dynsmem[];
  unsigned short* p_lds = (unsigned short*)dynsmem;

  const int tid  = threadIdx.x;
  const int lane = tid & 63;
  const int w    = tid >> 6;
  const int row  = blockIdx.x * 256 + tid;
  unsigned short* my_p = p_lds + (size_t)(w * 64 + lane) * 258;

  float xr[32];
  {
    const float4* xv = (const float4*)(x_in + (size_t)row * 32);
#pragma unroll
    for (int j = 0; j < 8; ++j) {
      float4 v = xv[j];
      xr[4*j+0] = v.x; xr[4*j+1] = v.y; xr[4*j+2] = v.z; xr[4*j+3] = v.w;
    }
  }
  float q[32];
#pragma unroll
  for (int d = 0; d < 32; ++d) q[d] = 0.0f;

  float ssum = 0.0f;
  float tmax = -3.0e38f;
  int   imax = 0;

  const float4* g4 = (const float4*)(gum + (size_t)row * 256);
  const float4* e4 = (const float4*)emb;

  for (int kg = 0; kg < 8; ++kg) {
    float uv[32];
#pragma unroll
    for (int j = 0; j < 8; ++j) {
      float4 v = g4[kg * 8 + j];
      uv[4*j+0] = v.x; uv[4*j+1] = v.y; uv[4*j+2] = v.z; uv[4*j+3] = v.w;
    }
#pragma unroll
    for (int kk = 0; kk < 32; ++kk) {
      const int k = kg * 32 + kk;
      float er[32];
#pragma unroll
      for (int j = 0; j < 8; ++j) {
        float4 v = e4[k * 8 + j];
        er[4*j+0] = v.x; er[4*j+1] = v.y; er[4*j+2] = v.z; er[4*j+3] = v.w;
      }
      float d0 = 0.f, d1 = 0.f, d2 = 0.f, d3 = 0.f;
#pragma unroll
      for (int d = 0; d < 32; d += 4) {
        d0 = fmaf(xr[d+0], er[d+0], d0);
        d1 = fmaf(xr[d+1], er[d+1], d1);
        d2 = fmaf(xr[d+2], er[d+2], d2);
        d3 = fmaf(xr[d+3], er[d+3], d3);
      }
      const float dot = (d0 + d1) + (d2 + d3);
      const float inner = -__logf(uv[kk] + 1e-20f);
      const float g = -__logf(inner + 1e-20f);
      const float t = fmaf(2.0f, dot, g) - ne[k];
      const float p = __expf(t);
      ssum += p;
      if (t > tmax) { tmax = t; imax = k; }
#pragma unroll
      for (int d = 0; d < 32; ++d) q[d] = fmaf(p, er[d], q[d]);
      my_p[k] = (unsigned short)f2bf_u(p);
    }
  }

  const float invS = 1.0f / ssum;
  {
    const float tr  = 1.0f / 3.0f;
    const float otr = 1.0f - tr;
    const float4* ehv = (const float4*)(emb + (size_t)imax * 32);
    float4* outq = (float4*)(out + (size_t)row * 32);
    float cl = 0.0f;
#pragma unroll
    for (int j = 0; j < 8; ++j) {
      float4 e = ehv[j];
      float4 o;
      float qs, dx;
      qs = q[4*j+0]*invS; o.x = tr*qs + otr*e.x; dx = e.x - xr[4*j+0]; cl = fmaf(dx,dx,cl);
      qs = q[4*j+1]*invS; o.y = tr*qs + otr*e.y; dx = e.y - xr[4*j+1]; cl = fmaf(dx,dx,cl);
      qs = q[4*j+2]*invS; o.z = tr*qs + otr*e.z; dx = e.z - xr[4*j+2]; cl = fmaf(dx,dx,cl);
      qs = q[4*j+3]*invS; o.w = tr*qs + otr*e.w; dx = e.w - xr[4*j+3]; cl = fmaf(dx,dx,cl);
      outq[j] = o;
    }
    out[OUT_IDX + row] = (float)imax;
#pragma unroll
    for (int off = 32; off > 0; off >>= 1) cl += __shfl_down(cl, off);
    if (lane == 0) atomicAdd(loss_ws, cl);
  }

  __syncthreads();

  float a0 = 0.f, a1 = 0.f, a2 = 0.f, a3 = 0.f;
  for (int r = 0; r < 64; ++r) {
    const float invS_r = __shfl(invS, r);
    const unsigned short* rp = p_lds + (size_t)(w * 64 + r) * 258;
    a0 = fmaf(bf2f(rp[  0 + lane]), invS_r, a0);
    a1 = fmaf(bf2f(rp[ 64 + lane]), invS_r, a1);
    a2 = fmaf(bf2f(rp[128 + lane]), invS_r, a2);
    a3 = fmaf(bf2f(rp[192 + lane]), invS_r, a3);
  }
  atomicAdd(&avg_ws[  0 + lane], a0);
  atomicAdd(&avg_ws[ 64 + lane], a1);
  atomicAdd(&avg_ws[128 + lane], a2);
  atomicAdd(&avg_ws[192 + lane], a3);
}

extern "C" void kernel_launch(void* const* d_in, const int* in_sizes, int n_in,
                              void* d_out, int out_size, void* d_ws, size_t ws_size,
                              hipStream_t stream) {
  const float* x   = (const float*)d_in[0];
  const float* emb = (const float*)d_in[1];
  const float* gum = (const float*)d_in[2];
  float* out = (float*)d_out;
  float* ws  = (float*)d_ws;

  (void)in_sizes; (void)n_in; (void)out_size;

  vq_prep<<<1, 256, 0, stream>>>(emb, ws);

  const size_t need = (size_t)(1024 + M_ROWS) * 4 + (size_t)M_ROWS * 256 * 2;
  if (ws_size >= need) {
    float* invS = ws + 1024;
    unsigned short* p = (unsigned short*)(ws + 1024 + M_ROWS);
    vq_pass1<<<2048, 256, 0, stream>>>(x, emb, gum, ws + 257, invS, p, ws + 256, out);
    vq_pass2<<<2048, 256, 0, stream>>>(emb, p, invS, out);
    vq_avg<<<1024, 256, 0, stream>>>(p, invS, ws);
  } else {
    hipFuncSetAttribute((const void*)vq_main,
                        hipFuncAttributeMaxDynamicSharedMemorySize, 132128);
    vq_main<<<1024, 256, 132128, stream>>>(x, emb, gum, ws + 257, ws, ws + 256, out);
  }
  vq_fin<<<1, 256, 0, stream>>>(ws, out);
}

// Round 6
// 427.577 us; speedup vs baseline: 3.1228x; 1.9174x over previous
//
#include <hip/hip_runtime.h>

// GumbelVQ — 3-pass streaming, row split across 2 wave-halves for occupancy.
// Outputs (concatenated float32 in d_out):
//   [0 .. 8388607]      quantized  [16,16384,32]
//   [8388608]           commitment_loss (scalar)
//   [8388609 .. 8650752] indices   [16,16384] (stored as float)
//   [8650753]           perplexity (scalar)
//
// ws float layout:
//   [0..255]    avg_probs accumulator
//   [256]       loss accumulator
//   [257..512]  ||e_k||^2
//   [1024 .. 1024+M)  invS per row
//   floats from 1024+M : p (unnormalized numerators) bf16 [M][256]
//
// Round-6 fix vs round-5: SGPR 80->32 showed the embedding loads fell off the
// scalar path — kbase=(tid>>7)*128 made the code index formally thread-
// dependent, so every e4[k*8+jj] became a per-lane global_load (10x VMEM issue
// + address VALU; pass1 300->459 us). readfirstlane(kbase) puts it back in an
// SGPR; k is scalar again -> s_load broadcast, as in round 3 (SGPR=80).

#define M_ROWS  262144
#define OUT_LOSS 8388608
#define OUT_IDX  8388609
#define OUT_PPL  8650753

__device__ __forceinline__ unsigned int f2bf_u(float f) {
  unsigned int u = __float_as_uint(f);
  u += 0x7fffu + ((u >> 16) & 1u);
  return u >> 16;
}
__device__ __forceinline__ float bf2f(unsigned int lo16) {
  return __uint_as_float(lo16 << 16);
}

__global__ __launch_bounds__(256) void vq_prep(const float* __restrict__ emb,
                                               float* __restrict__ ws) {
  int t = threadIdx.x;
  ws[t] = 0.0f;                 // avg accumulators
  if (t == 0) ws[256] = 0.0f;   // loss accumulator
  const float4* e4 = (const float4*)emb;
  float s = 0.0f;
#pragma unroll
  for (int j = 0; j < 8; ++j) {
    float4 v = e4[t * 8 + j];
    s += v.x * v.x + v.y * v.y + v.z * v.z + v.w * v.w;
  }
  ws[257 + t] = s;
}

// ---- pass 1: logits, p(bf16)->ws, invS, argmax->indices, loss ---------------
// 2048 blocks x 256 thr; block owns 128 rows; half = tid>>7 owns 128 codes.
__global__ __launch_bounds__(256, 4) void vq_pass1(
    const float* __restrict__ x_in, const float* __restrict__ emb,
    const float* __restrict__ gum, const float* __restrict__ ne,
    float* __restrict__ invS_ws, unsigned short* __restrict__ p_ws,
    float* __restrict__ loss_ws, float* __restrict__ out) {
  __shared__ float sh_ssum[128];
  __shared__ float sh_tmax[128];
  __shared__ int   sh_imax[128];

  const int tid  = threadIdx.x;
  const int lane = tid & 63;
  const int rloc = tid & 127;
  const int half = tid >> 7;
  // wave-uniform by construction; readfirstlane makes that visible -> SGPR.
  const int kbase = __builtin_amdgcn_readfirstlane(half * 128);
  const int row  = blockIdx.x * 128 + rloc;

  float xr[32];
  {
    const float4* xv = (const float4*)(x_in + (size_t)row * 32);
#pragma unroll
    for (int j = 0; j < 8; ++j) {
      float4 v = xv[j];
      xr[4*j+0] = v.x; xr[4*j+1] = v.y; xr[4*j+2] = v.z; xr[4*j+3] = v.w;
    }
  }

  const float4* g4 = (const float4*)(gum + (size_t)row * 256 + kbase);
  const float4* e4 = (const float4*)emb;
  uint4* pout = (uint4*)(p_ws + (size_t)row * 256 + kbase);

  float ssum = 0.0f;
  float tmax = -3.0e38f;
  int   imax = 0;

  for (int kg = 0; kg < 4; ++kg) {          // 4 groups of 32 codes
    float uv[32];
#pragma unroll
    for (int j = 0; j < 8; ++j) {
      float4 v = g4[kg * 8 + j];
      uv[4*j+0] = v.x; uv[4*j+1] = v.y; uv[4*j+2] = v.z; uv[4*j+3] = v.w;
    }
    unsigned int packs[16];
#pragma unroll
    for (int kk = 0; kk < 32; ++kk) {
      const int k = kbase + kg * 32 + kk;   // scalar (SGPR + consts)
      const float g = -__logf(-__logf(uv[kk] + 1e-20f) + 1e-20f);
      float d0 = 0.f, d1 = 0.f, d2 = 0.f, d3 = 0.f;
#pragma unroll
      for (int jj = 0; jj < 8; ++jj) {
        const float4 e = e4[k * 8 + jj];    // uniform -> s_load broadcast
        d0 = fmaf(xr[4*jj+0], e.x, d0);
        d1 = fmaf(xr[4*jj+1], e.y, d1);
        d2 = fmaf(xr[4*jj+2], e.z, d2);
        d3 = fmaf(xr[4*jj+3], e.w, d3);
      }
      const float dot = (d0 + d1) + (d2 + d3);
      const float t = fmaf(2.0f, dot, g) - ne[k];  // ||x||^2 const per row
      const float p = __expf(t);
      ssum += p;
      if (t > tmax) { tmax = t; imax = k; }
      if (kk & 1) packs[kk >> 1] |= f2bf_u(p) << 16;
      else        packs[kk >> 1]  = f2bf_u(p);
    }
    const uint4* pd = (const uint4*)packs;
#pragma unroll
    for (int j = 0; j < 4; ++j) pout[kg * 4 + j] = pd[j];  // full 64B line
  }

  if (half == 1) {
    sh_ssum[rloc] = ssum; sh_tmax[rloc] = tmax; sh_imax[rloc] = imax;
  }
  __syncthreads();
  if (half == 0) {
    const float sB = sh_ssum[rloc];
    const float tB = sh_tmax[rloc];
    const int   iB = sh_imax[rloc];
    if (tB > tmax) { tmax = tB; imax = iB; }   // strict > keeps first-index ties
    invS_ws[row] = 1.0f / (ssum + sB);
    out[OUT_IDX + row] = (float)imax;

    // commitment loss: (e_hard - x)^2 summed; e gather is L1-resident (32KB)
    const float4* ehv = (const float4*)(emb + (size_t)imax * 32);
    float cl = 0.0f;
#pragma unroll
    for (int j = 0; j < 8; ++j) {
      float4 e = ehv[j];
      float dx;
      dx = e.x - xr[4*j+0]; cl = fmaf(dx, dx, cl);
      dx = e.y - xr[4*j+1]; cl = fmaf(dx, dx, cl);
      dx = e.z - xr[4*j+2]; cl = fmaf(dx, dx, cl);
      dx = e.w - xr[4*j+3]; cl = fmaf(dx, dx, cl);
    }
#pragma unroll
    for (int off = 32; off > 0; off >>= 1) cl += __shfl_down(cl, off);
    if (lane == 0) atomicAdd(loss_ws, cl);
  }
}

// ---- pass 2: quantized = tr * (p-hat @ E) + (1-tr) * e_hard -----------------
// Same split: half-B accumulates q over codes 128..255, hands it over via LDS.
__global__ __launch_bounds__(256, 4) void vq_pass2(
    const float* __restrict__ emb, const unsigned short* __restrict__ p_ws,
    const float* __restrict__ invS_ws, float* __restrict__ out) {
  __shared__ float shq[128][33];            // +1 pad: conflict-free columns

  const int tid  = threadIdx.x;
  const int rloc = tid & 127;
  const int half = tid >> 7;
  const int kbase = __builtin_amdgcn_readfirstlane(half * 128);  // SGPR
  const int row  = blockIdx.x * 128 + rloc;

  const uint4* pv = (const uint4*)(p_ws + (size_t)row * 256 + kbase);
  const float4* e4 = (const float4*)emb;

  float q[32];
#pragma unroll
  for (int d = 0; d < 32; ++d) q[d] = 0.0f;

  for (int i = 0; i < 16; ++i) {            // 16 uint4 = 128 codes per half
    const uint4 v = pv[i];
    unsigned int w_[4] = {v.x, v.y, v.z, v.w};
#pragma unroll
    for (int h = 0; h < 4; ++h) {
      const int k0 = kbase + i * 8 + 2 * h; // scalar
      const float p0 = bf2f(w_[h] & 0xffffu);
      const float p1 = bf2f(w_[h] >> 16);
#pragma unroll
      for (int jj = 0; jj < 8; ++jj) {
        const float4 e0 = e4[k0 * 8 + jj];        // uniform -> s_load
        const float4 e1 = e4[(k0 + 1) * 8 + jj];
        q[4*jj+0] = fmaf(p0, e0.x, fmaf(p1, e1.x, q[4*jj+0]));
        q[4*jj+1] = fmaf(p0, e0.y, fmaf(p1, e1.y, q[4*jj+1]));
        q[4*jj+2] = fmaf(p0, e0.z, fmaf(p1, e1.z, q[4*jj+2]));
        q[4*jj+3] = fmaf(p0, e0.w, fmaf(p1, e1.w, q[4*jj+3]));
      }
    }
  }

  if (half == 1) {
#pragma unroll
    for (int d = 0; d < 32; ++d) shq[rloc][d] = q[d];
  }
  __syncthreads();
  if (half == 0) {
    const float invS = invS_ws[row];
    const int imax = (int)out[OUT_IDX + row];
    const float tr  = 1.0f / 3.0f;     // (1.0-0.5)/(2.0-0.5)
    const float otr = 1.0f - tr;
    const float4* ehv = (const float4*)(emb + (size_t)imax * 32);
    float4* outq = (float4*)(out + (size_t)row * 32);
#pragma unroll
    for (int j = 0; j < 8; ++j) {
      float4 e = ehv[j];
      float4 o;
      o.x = fmaf(tr, (q[4*j+0] + shq[rloc][4*j+0]) * invS, otr * e.x);
      o.y = fmaf(tr, (q[4*j+1] + shq[rloc][4*j+1]) * invS, otr * e.y);
      o.z = fmaf(tr, (q[4*j+2] + shq[rloc][4*j+2]) * invS, otr * e.z);
      o.w = fmaf(tr, (q[4*j+3] + shq[rloc][4*j+3]) * invS, otr * e.w);
      outq[j] = o;
    }
  }
}

// ---- pass 2b: avg_probs column sums (coalesced, 4096 waves) -----------------
__global__ __launch_bounds__(256) void vq_avg(
    const unsigned short* __restrict__ p_ws, const float* __restrict__ invS_ws,
    float* __restrict__ avg_ws) {
  __shared__ float sh[256];
  const int tid = threadIdx.x, lane = tid & 63, w = tid >> 6;
  sh[tid] = 0.0f;
  __syncthreads();
  const int base = (blockIdx.x * 4 + w) * 64;   // 4096 waves, 64 rows each
  const float iv = invS_ws[base + lane];
  float a0 = 0.f, a1 = 0.f, a2 = 0.f, a3 = 0.f;
  for (int r = 0; r < 64; ++r) {
    const float s = __shfl(iv, r);
    const unsigned short* pr = p_ws + (size_t)(base + r) * 256;
    a0 = fmaf(bf2f(pr[  0 + lane]), s, a0);
    a1 = fmaf(bf2f(pr[ 64 + lane]), s, a1);
    a2 = fmaf(bf2f(pr[128 + lane]), s, a2);
    a3 = fmaf(bf2f(pr[192 + lane]), s, a3);
  }
  atomicAdd(&sh[  0 + lane], a0);
  atomicAdd(&sh[ 64 + lane], a1);
  atomicAdd(&sh[128 + lane], a2);
  atomicAdd(&sh[192 + lane], a3);
  __syncthreads();
  atomicAdd(&avg_ws[tid], sh[tid]);
}

__global__ __launch_bounds__(256) void vq_fin(const float* __restrict__ ws,
                                              float* __restrict__ out) {
  __shared__ float red[256];
  int t = threadIdx.x;
  float avg = ws[t] * (1.0f / 262144.0f);
  red[t] = -avg * __logf(avg + 1e-10f);
  __syncthreads();
  for (int s = 128; s > 0; s >>= 1) {
    if (t < s) red[t] += red[t + s];
    __syncthreads();
  }
  if (t == 0) {
    out[OUT_PPL]  = __expf(red[0]);
    out[OUT_LOSS] = ws[256] * (1.0f / 8388608.0f);
  }
}

// ---- fallback (round-1 monolithic, if ws too small) -------------------------
__global__ __launch_bounds__(256, 1) void vq_main(
    const float* __restrict__ x_in, const float* __restrict__ emb,
    const float* __restrict__ gum, const float* __restrict__ ne,
    float* __restrict__ avg_ws, float* __restrict__ loss_ws,
    float* __restrict__ out) {
  extern __shared__ unsigned char dynsmem[];
  unsigned short* p_lds = (unsigned short*)dynsmem;

  const int tid  = threadIdx.x;
  const int lane = tid & 63;
  const int w    = tid >> 6;
  const int row  = blockIdx.x * 256 + tid;
  unsigned short* my_p = p_lds + (size_t)(w * 64 + lane) * 258;

  float xr[32];
  {
    const float4* xv = (const float4*)(x_in + (size_t)row * 32);
#pragma unroll
    for (int j = 0; j < 8; ++j) {
      float4 v = xv[j];
      xr[4*j+0] = v.x; xr[4*j+1] = v.y; xr[4*j+2] = v.z; xr[4*j+3] = v.w;
    }
  }
  float q[32];
#pragma unroll
  for (int d = 0; d < 32; ++d) q[d] = 0.0f;

  float ssum = 0.0f;
  float tmax = -3.0e38f;
  int   imax = 0;

  const float4* g4 = (const float4*)(gum + (size_t)row * 256);
  const float4* e4 = (const float4*)emb;

  for (int kg = 0; kg < 8; ++kg) {
    float uv[32];
#pragma unroll
    for (int j = 0; j < 8; ++j) {
      float4 v = g4[kg * 8 + j];
      uv[4*j+0] = v.x; uv[4*j+1] = v.y; uv[4*j+2] = v.z; uv[4*j+3] = v.w;
    }
#pragma unroll
    for (int kk = 0; kk < 32; ++kk) {
      const int k = kg * 32 + kk;
      float er[32];
#pragma unroll
      for (int j = 0; j < 8; ++j) {
        float4 v = e4[k * 8 + j];
        er[4*j+0] = v.x; er[4*j+1] = v.y; er[4*j+2] = v.z; er[4*j+3] = v.w;
      }
      float d0 = 0.f, d1 = 0.f, d2 = 0.f, d3 = 0.f;
#pragma unroll
      for (int d = 0; d < 32; d += 4) {
        d0 = fmaf(xr[d+0], er[d+0], d0);
        d1 = fmaf(xr[d+1], er[d+1], d1);
        d2 = fmaf(xr[d+2], er[d+2], d2);
        d3 = fmaf(xr[d+3], er[d+3], d3);
      }
      const float dot = (d0 + d1) + (d2 + d3);
      const float inner = -__logf(uv[kk] + 1e-20f);
      const float g = -__logf(inner + 1e-20f);
      const float t = fmaf(2.0f, dot, g) - ne[k];
      const float p = __expf(t);
      ssum += p;
      if (t > tmax) { tmax = t; imax = k; }
#pragma unroll
      for (int d = 0; d < 32; ++d) q[d] = fmaf(p, er[d], q[d]);
      my_p[k] = (unsigned short)f2bf_u(p);
    }
  }

  const float invS = 1.0f / ssum;
  {
    const float tr  = 1.0f / 3.0f;
    const float otr = 1.0f - tr;
    const float4* ehv = (const float4*)(emb + (size_t)imax * 32);
    float4* outq = (float4*)(out + (size_t)row * 32);
    float cl = 0.0f;
#pragma unroll
    for (int j = 0; j < 8; ++j) {
      float4 e = ehv[j];
      float4 o;
      float qs, dx;
      qs = q[4*j+0]*invS; o.x = tr*qs + otr*e.x; dx = e.x - xr[4*j+0]; cl = fmaf(dx,dx,cl);
      qs = q[4*j+1]*invS; o.y = tr*qs + otr*e.y; dx = e.y - xr[4*j+1]; cl = fmaf(dx,dx,cl);
      qs = q[4*j+2]*invS; o.z = tr*qs + otr*e.z; dx = e.z - xr[4*j+2]; cl = fmaf(dx,dx,cl);
      qs = q[4*j+3]*invS; o.w = tr*qs + otr*e.w; dx = e.w - xr[4*j+3]; cl = fmaf(dx,dx,cl);
      outq[j] = o;
    }
    out[OUT_IDX + row] = (float)imax;
#pragma unroll
    for (int off = 32; off > 0; off >>= 1) cl += __shfl_down(cl, off);
    if (lane == 0) atomicAdd(loss_ws, cl);
  }

  __syncthreads();

  float a0 = 0.f, a1 = 0.f, a2 = 0.f, a3 = 0.f;
  for (int r = 0; r < 64; ++r) {
    const float invS_r = __shfl(invS, r);
    const unsigned short* rp = p_lds + (size_t)(w * 64 + r) * 258;
    a0 = fmaf(bf2f(rp[  0 + lane]), invS_r, a0);
    a1 = fmaf(bf2f(rp[ 64 + lane]), invS_r, a1);
    a2 = fmaf(bf2f(rp[128 + lane]), invS_r, a2);
    a3 = fmaf(bf2f(rp[192 + lane]), invS_r, a3);
  }
  atomicAdd(&avg_ws[  0 + lane], a0);
  atomicAdd(&avg_ws[ 64 + lane], a1);
  atomicAdd(&avg_ws[128 + lane], a2);
  atomicAdd(&avg_ws[192 + lane], a3);
}

extern "C" void kernel_launch(void* const* d_in, const int* in_sizes, int n_in,
                              void* d_out, int out_size, void* d_ws, size_t ws_size,
                              hipStream_t stream) {
  const float* x   = (const float*)d_in[0];
  const float* emb = (const float*)d_in[1];
  const float* gum = (const float*)d_in[2];
  float* out = (float*)d_out;
  float* ws  = (float*)d_ws;

  (void)in_sizes; (void)n_in; (void)out_size;

  vq_prep<<<1, 256, 0, stream>>>(emb, ws);

  const size_t need = (size_t)(1024 + M_ROWS) * 4 + (size_t)M_ROWS * 256 * 2;
  if (ws_size >= need) {
    float* invS = ws + 1024;
    unsigned short* p = (unsigned short*)(ws + 1024 + M_ROWS);
    vq_pass1<<<2048, 256, 0, stream>>>(x, emb, gum, ws + 257, invS, p, ws + 256, out);
    vq_pass2<<<2048, 256, 0, stream>>>(emb, p, invS, out);
    vq_avg<<<1024, 256, 0, stream>>>(p, invS, ws);
  } else {
    hipFuncSetAttribute((const void*)vq_main,
                        hipFuncAttributeMaxDynamicSharedMemorySize, 132128);
    vq_main<<<1024, 256, 132128, stream>>>(x, emb, gum, ws + 257, ws, ws + 256, out);
  }
  vq_fin<<<1, 256, 0, stream>>>(ws, out);
}